// Round 1
// baseline (474.748 us; speedup 1.0000x reference)
//
#include <hip/hip_runtime.h>
#include <hip/hip_bf16.h>
#include <math.h>

#define N_CELLS 1024
#define HID     256
#define IN_DIM  256
#define NOISE_DIM 32
#define OUT_DIM 256
#define N_LOOP  32
#define FLAT    (N_CELLS*HID)   // 262144

// ---------------- Kernel A: generator head (h1, h2) ----------------
__global__ void k_gen_head(const float* __restrict__ x, const float* __restrict__ noise,
                           const float* __restrict__ W1, const float* __restrict__ b1,
                           const float* __restrict__ W2, const float* __restrict__ b2,
                           float* __restrict__ h2out) {
    __shared__ __align__(16) float gi[288];
    __shared__ __align__(16) float h1[256];
    int t = threadIdx.x;
    gi[t] = x[t];
    if (t < 32) gi[256 + t] = noise[t];
    __syncthreads();
    {   // h1[t] = relu(W1[t,:] . gi + b1[t]), row length 288
        float acc = b1[t];
        const float4* wr = (const float4*)(W1 + t * 288);
        const float4* g4 = (const float4*)gi;
        for (int k = 0; k < 72; ++k) {
            float4 w = wr[k], v = g4[k];
            acc += w.x*v.x + w.y*v.y + w.z*v.z + w.w*v.w;
        }
        h1[t] = fmaxf(acc, 0.f);
    }
    __syncthreads();
    for (int j = t; j < 512; j += 256) {  // h2[j] = relu(W2[j,:] . h1 + b2[j])
        float acc = b2[j];
        const float4* wr = (const float4*)(W2 + j * 256);
        const float4* g4 = (const float4*)h1;
        for (int k = 0; k < 64; ++k) {
            float4 w = wr[k], v = g4[k];
            acc += w.x*v.x + w.y*v.y + w.z*v.z + w.w*v.w;
        }
        h2out[j] = fmaxf(acc, 0.f);
    }
}

// ---------------- Kernel B: gen_states = W3 . h2 + b3 (wave per row) ----------------
__global__ void k_gen_big(const float* __restrict__ W3, const float* __restrict__ b3,
                          const float* __restrict__ h2, float* __restrict__ gs) {
    int lane = threadIdx.x & 63;
    int row  = blockIdx.x * (blockDim.x >> 6) + (threadIdx.x >> 6);
    const float4* h24 = (const float4*)h2;       // 128 float4s
    float4 ha = h24[lane], hb = h24[64 + lane];
    const float4* w4 = (const float4*)(W3 + (size_t)row * 512);
    float4 wa = w4[lane], wb = w4[64 + lane];
    float acc = wa.x*ha.x + wa.y*ha.y + wa.z*ha.z + wa.w*ha.w
              + wb.x*hb.x + wb.y*hb.y + wb.z*hb.z + wb.w*hb.w;
    #pragma unroll
    for (int m = 32; m; m >>= 1) acc += __shfl_xor(acc, m);
    if (lane == 0) gs[row] = acc + b3[row];
}

// ---------------- Kernel C: per-faction column means ----------------
__global__ void k_fmean(const float* __restrict__ gs, float* __restrict__ fmean) {
    int f = blockIdx.x, d = threadIdx.x;
    float s = 0.f;
    const float* base = gs + (f * 128) * 256 + d;
    for (int i = 0; i < 128; ++i) s += base[i * 256];
    fmean[f * 256 + d] = s * (1.f / 128.f);
}

// ---------------- Kernel D: synced + new_cell_hiddens ----------------
__global__ void k_sync(const float* __restrict__ gs, const float* __restrict__ fmean,
                       const float* __restrict__ ch, const int* __restrict__ step,
                       float* __restrict__ synced, float* __restrict__ ncn) {
    int c = blockIdx.x, d = threadIdx.x;
    int f = c >> 7;
    float gm = 0.f;
    #pragma unroll
    for (int k = 0; k < 8; ++k) gm += fmean[k * 256 + d];
    gm *= 0.125f;
    float fm = fmean[f * 256 + d];
    float v = 0.85f * gs[c * 256 + d] + 0.15f * fm;
    if (((c & 127) < 32) && (*step > 5)) v = 0.85f * v + 0.15f * gm;
    synced[c * 256 + d] = v;
    ncn[c * 256 + d] = 0.7f * v + 0.3f * ch[c * 256 + d];
}

// ---------------- Kernel E: fused disc layer-1 for real+fake ----------------
__global__ void k_disc1(const float* __restrict__ W1, const float* __restrict__ b1,
                        const float* __restrict__ real, const float* __restrict__ fake,
                        float* __restrict__ d1r, float* __restrict__ d1f) {
    __shared__ float sR[1024];
    __shared__ float sF[1024];
    int row = blockIdx.x, t = threadIdx.x;
    const float4* w4 = (const float4*)(W1 + (size_t)row * FLAT);
    const float4* r4 = (const float4*)real;
    const float4* f4 = (const float4*)fake;
    float aR = 0.f, aF = 0.f;
    for (int i = t; i < FLAT / 4; i += 1024) {
        float4 w = w4[i], r = r4[i], f = f4[i];
        aR += w.x*r.x + w.y*r.y + w.z*r.z + w.w*r.w;
        aF += w.x*f.x + w.y*f.y + w.z*f.z + w.w*f.w;
    }
    sR[t] = aR; sF[t] = aF;
    __syncthreads();
    for (int m = 512; m; m >>= 1) {
        if (t < m) { sR[t] += sR[t + m]; sF[t] += sF[t + m]; }
        __syncthreads();
    }
    if (t == 0) { d1r[row] = sR[0] + b1[row]; d1f[row] = sF[0] + b1[row]; }
}

// ---------------- Kernel F: disc layers 2+3 (block 0 = real, block 1 = fake) ----------------
__global__ void k_disc_tail(const float* __restrict__ W2, const float* __restrict__ b2,
                            const float* __restrict__ W3, const float* __restrict__ b3,
                            const float* __restrict__ d1r, const float* __restrict__ d1f,
                            float* __restrict__ out) {
    __shared__ __align__(16) float lv[512];
    __shared__ float l2[256];
    __shared__ float red[256];
    int b = blockIdx.x, t = threadIdx.x;
    const float* d1 = b ? d1f : d1r;
    for (int j = t; j < 512; j += 256) { float v = d1[j]; lv[j] = v > 0.f ? v : 0.2f * v; }
    __syncthreads();
    {
        float acc = b2[t];
        const float4* wr = (const float4*)(W2 + t * 512);
        const float4* l4 = (const float4*)lv;
        for (int k = 0; k < 128; ++k) {
            float4 w = wr[k], v = l4[k];
            acc += w.x*v.x + w.y*v.y + w.z*v.z + w.w*v.w;
        }
        l2[t] = acc > 0.f ? acc : 0.2f * acc;
    }
    __syncthreads();
    red[t] = l2[t] * W3[t];
    __syncthreads();
    for (int m = 128; m; m >>= 1) { if (t < m) red[t] += red[t + m]; __syncthreads(); }
    if (t == 0) { float v = red[0] + b3[0]; out[257 + b] = 1.f / (1.f + expf(-v)); }
}

// ---------------- Kernel G1: evaluator MLPs + GRU (block per loop row) ----------------
__global__ void k_eval_gru(const float* __restrict__ x, const float* __restrict__ synced,
                           const float* __restrict__ eaW1, const float* __restrict__ eab1,
                           const float* __restrict__ eaW2, const float* __restrict__ eab2,
                           const float* __restrict__ egW1, const float* __restrict__ egb1,
                           const float* __restrict__ egW2, const float* __restrict__ egb2,
                           const float* __restrict__ Wih, const float* __restrict__ bih,
                           const float* __restrict__ Whh, const float* __restrict__ bhh,
                           float* __restrict__ outputs, float* __restrict__ tensions,
                           float* __restrict__ out) {
    __shared__ __align__(16) float comb[512];
    __shared__ __align__(16) float ha[128];
    __shared__ __align__(16) float hg[128];
    __shared__ __align__(16) float outs[256];
    __shared__ float red[256];
    __shared__ float tshared;
    int i = blockIdx.x, t = threadIdx.x;
    comb[t]       = x[t];
    comb[256 + t] = synced[i * 256 + t];   // H row
    __syncthreads();
    {   // layer 1: threads 0..127 -> ha, 128..255 -> hg
        int j = t & 127;
        const float* W  = (t < 128) ? eaW1 : egW1;
        const float* bb = (t < 128) ? eab1 : egb1;
        float acc = bb[j];
        const float4* wr = (const float4*)(W + j * 512);
        const float4* c4 = (const float4*)comb;
        for (int k = 0; k < 128; ++k) {
            float4 w = wr[k], v = c4[k];
            acc += w.x*v.x + w.y*v.y + w.z*v.z + w.w*v.w;
        }
        acc = fmaxf(acc, 0.f);
        if (t < 128) ha[j] = acc; else hg[j] = acc;
    }
    __syncthreads();
    {   // layer 2: outputs = a - g
        float sa = eab2[t], sg_ = egb2[t];
        const float4* wa  = (const float4*)(eaW2 + t * 128);
        const float4* wg  = (const float4*)(egW2 + t * 128);
        const float4* h4a = (const float4*)ha;
        const float4* h4g = (const float4*)hg;
        for (int k = 0; k < 32; ++k) {
            float4 w = wa[k], v = h4a[k];   sa  += w.x*v.x + w.y*v.y + w.z*v.z + w.w*v.w;
            float4 w2 = wg[k], v2 = h4g[k]; sg_ += w2.x*v2.x + w2.y*v2.y + w2.z*v2.z + w2.w*v2.w;
        }
        float o = sa - sg_;
        outs[t] = o;
        outputs[i * 256 + t] = o;
        red[t] = o * o;
    }
    __syncthreads();
    for (int m = 128; m; m >>= 1) { if (t < m) red[t] += red[t + m]; __syncthreads(); }
    if (t == 0) { float tn = red[0] * (1.f / 256.f); tensions[i] = tn; tshared = tn; }
    __syncthreads();
    {   // GRU for dim d = t
        float tn = tshared;
        float g[3], h[3];
        #pragma unroll
        for (int r = 0; r < 3; ++r) {   // gih rows t, t+256, t+512 (row length 257)
            int u = t + r * 256;
            const float* wr = Wih + (size_t)u * 257;
            float acc = bih[u];
            for (int k = 0; k < 256; ++k) acc += wr[k] * outs[k];
            acc += wr[256] * tn;
            g[r] = acc;
        }
        #pragma unroll
        for (int r = 0; r < 3; ++r) {   // ghh rows
            int u = t + r * 256;
            const float4* wr = (const float4*)(Whh + (size_t)u * 256);
            const float4* c4 = (const float4*)(comb + 256);
            float acc = bhh[u];
            for (int k = 0; k < 64; ++k) {
                float4 w = wr[k], v = c4[k];
                acc += w.x*v.x + w.y*v.y + w.z*v.z + w.w*v.w;
            }
            h[r] = acc;
        }
        float r_ = 1.f / (1.f + expf(-(g[0] + h[0])));
        float z  = 1.f / (1.f + expf(-(g[1] + h[1])));
        float nc = tanhf(g[2] + r_ * h[2]);
        float Hd = comb[256 + t];
        out[259 + i * 256 + t] = (1.f - z) * nc + z * Hd;
    }
}

// ---------------- Kernel G2: mean_tension + softmax-weighted combine ----------------
__global__ void k_combine(const float* __restrict__ outputs, const float* __restrict__ tensions,
                          float* __restrict__ out) {
    __shared__ float w[32];
    __shared__ float ts[32];
    int t = threadIdx.x;
    if (t < 32) ts[t] = tensions[t];
    __syncthreads();
    if (t == 0) {
        float mx = ts[0];
        for (int i = 1; i < 32; ++i) mx = fmaxf(mx, ts[i]);
        float s = 0.f, mean = 0.f;
        for (int i = 0; i < 32; ++i) { float e = expf(ts[i] - mx); w[i] = e; s += e; mean += ts[i]; }
        float inv = 1.f / s;
        for (int i = 0; i < 32; ++i) w[i] *= inv;
        out[256] = mean * (1.f / 32.f);
    }
    __syncthreads();
    float c = 0.f;
    for (int i = 0; i < 32; ++i) c += w[i] * outputs[i * 256 + t];
    out[t] = c;
}

extern "C" void kernel_launch(void* const* d_in, const int* in_sizes, int n_in,
                              void* d_out, int out_size, void* d_ws, size_t ws_size,
                              hipStream_t stream) {
    const float* x     = (const float*)d_in[0];
    const float* noise = (const float*)d_in[1];
    const float* ch    = (const float*)d_in[2];
    const float* gW1   = (const float*)d_in[3];
    const float* gb1   = (const float*)d_in[4];
    const float* gW2   = (const float*)d_in[5];
    const float* gb2   = (const float*)d_in[6];
    const float* gW3   = (const float*)d_in[7];
    const float* gb3   = (const float*)d_in[8];
    const float* dW1   = (const float*)d_in[9];
    const float* db1   = (const float*)d_in[10];
    const float* dW2   = (const float*)d_in[11];
    const float* db2   = (const float*)d_in[12];
    const float* dW3   = (const float*)d_in[13];
    const float* db3   = (const float*)d_in[14];
    const float* eaW1  = (const float*)d_in[15];
    const float* eab1  = (const float*)d_in[16];
    const float* eaW2  = (const float*)d_in[17];
    const float* eab2  = (const float*)d_in[18];
    const float* egW1  = (const float*)d_in[19];
    const float* egb1  = (const float*)d_in[20];
    const float* egW2  = (const float*)d_in[21];
    const float* egb2  = (const float*)d_in[22];
    const float* Wih   = (const float*)d_in[23];
    const float* bih   = (const float*)d_in[24];
    const float* Whh   = (const float*)d_in[25];
    const float* bhh   = (const float*)d_in[26];
    const int*   step  = (const int*)d_in[27];

    float* out = (float*)d_out;
    float* ws  = (float*)d_ws;
    float* h2       = ws;                 // 512
    float* gs       = ws + 512;           // 262144
    float* fmean    = gs + 262144;        // 2048
    float* synced   = fmean + 2048;       // 262144
    float* ncn      = synced + 262144;    // 262144
    float* d1r      = ncn + 262144;       // 512
    float* d1f      = d1r + 512;          // 512
    float* outputs  = d1f + 512;          // 8192
    float* tensions = outputs + 8192;     // 32

    k_gen_head<<<1, 256, 0, stream>>>(x, noise, gW1, gb1, gW2, gb2, h2);
    k_gen_big<<<FLAT / 4, 256, 0, stream>>>(gW3, gb3, h2, gs);
    k_fmean<<<8, 256, 0, stream>>>(gs, fmean);
    k_sync<<<1024, 256, 0, stream>>>(gs, fmean, ch, step, synced, ncn);
    k_disc1<<<512, 1024, 0, stream>>>(dW1, db1, ncn, gs, d1r, d1f);
    k_disc_tail<<<2, 256, 0, stream>>>(dW2, db2, dW3, db3, d1r, d1f, out);
    k_eval_gru<<<32, 256, 0, stream>>>(x, synced, eaW1, eab1, eaW2, eab2,
                                       egW1, egb1, egW2, egb2,
                                       Wih, bih, Whh, bhh, outputs, tensions, out);
    k_combine<<<1, 256, 0, stream>>>(outputs, tensions, out);
}

// Round 2
// 302.513 us; speedup vs baseline: 1.5693x; 1.5693x over previous
//
#include <hip/hip_runtime.h>
#include <hip/hip_bf16.h>
#include <math.h>

#define N_CELLS 1024
#define HID     256
#define IN_DIM  256
#define NOISE_DIM 32
#define OUT_DIM 256
#define N_LOOP  32
#define FLAT    (N_CELLS*HID)   // 262144

__device__ __forceinline__ float wave_reduce64(float v) {
    #pragma unroll
    for (int m = 32; m; m >>= 1) v += __shfl_xor(v, m);
    return v;
}
__device__ __forceinline__ float wave_reduce32(float v) {
    #pragma unroll
    for (int m = 16; m; m >>= 1) v += __shfl_xor(v, m);
    return v;
}

// ---------------- h1 = relu(W1 . gi + b1), wave-per-row (256 rows x 288) ----------------
__global__ void k_gen_h1(const float* __restrict__ x, const float* __restrict__ noise,
                         const float* __restrict__ W1, const float* __restrict__ b1,
                         float* __restrict__ h1) {
    __shared__ __align__(16) float gi[288];
    int t = threadIdx.x, l = t & 63, w = t >> 6;
    gi[t] = x[t];
    if (t < 32) gi[256 + t] = noise[t];
    __syncthreads();
    int j = blockIdx.x * 4 + w;
    const float4* wr = (const float4*)(W1 + j * 288);   // 72 float4
    const float4* g4 = (const float4*)gi;
    float4 a = wr[l], v = g4[l];
    float acc = a.x*v.x + a.y*v.y + a.z*v.z + a.w*v.w;
    if (l < 8) {
        float4 a2 = wr[64 + l], v2 = g4[64 + l];
        acc += a2.x*v2.x + a2.y*v2.y + a2.z*v2.z + a2.w*v2.w;
    }
    acc = wave_reduce64(acc);
    if (l == 0) h1[j] = fmaxf(acc + b1[j], 0.f);
}

// ---------------- h2 = relu(W2 . h1 + b2), wave-per-row (512 rows x 256) ----------------
__global__ void k_gen_h2(const float* __restrict__ h1, const float* __restrict__ W2,
                         const float* __restrict__ b2, float* __restrict__ h2) {
    int t = threadIdx.x, l = t & 63, w = t >> 6;
    int j = blockIdx.x * 4 + w;
    float4 a = ((const float4*)(W2 + j * 256))[l];
    float4 v = ((const float4*)h1)[l];
    float acc = a.x*v.x + a.y*v.y + a.z*v.z + a.w*v.w;
    acc = wave_reduce64(acc);
    if (l == 0) h2[j] = fmaxf(acc + b2[j], 0.f);
}

// ---------------- gen_states = W3 . h2 + b3 (wave per row) ----------------
__global__ void k_gen_big(const float* __restrict__ W3, const float* __restrict__ b3,
                          const float* __restrict__ h2, float* __restrict__ gs) {
    int lane = threadIdx.x & 63;
    int row  = blockIdx.x * (blockDim.x >> 6) + (threadIdx.x >> 6);
    const float4* h24 = (const float4*)h2;       // 128 float4s
    float4 ha = h24[lane], hb = h24[64 + lane];
    const float4* w4 = (const float4*)(W3 + (size_t)row * 512);
    float4 wa = w4[lane], wb = w4[64 + lane];
    float acc = wa.x*ha.x + wa.y*ha.y + wa.z*ha.z + wa.w*ha.w
              + wb.x*hb.x + wb.y*hb.y + wb.z*hb.z + wb.w*hb.w;
    acc = wave_reduce64(acc);
    if (lane == 0) gs[row] = acc + b3[row];
}

// ---------------- per-faction column means: block = (faction, 64-col chunk) ----------------
__global__ void k_fmean(const float* __restrict__ gs, float* __restrict__ fmean) {
    __shared__ float part[4][64];
    int b = blockIdx.x, t = threadIdx.x;
    int f = b >> 2, q = b & 3;
    int c = q * 64 + (t & 63), rg = t >> 6;
    const float* base = gs + (size_t)(f * 128 + rg * 32) * 256 + c;
    float s = 0.f;
    for (int i = 0; i < 32; ++i) s += base[(size_t)i * 256];
    part[rg][t & 63] = s;
    __syncthreads();
    if (t < 64) {
        float v = part[0][t] + part[1][t] + part[2][t] + part[3][t];
        fmean[f * 256 + q * 64 + t] = v * (1.f / 128.f);
    }
}

// ---------------- synced + new_cell_hiddens + comb rows ----------------
__global__ void k_sync(const float* __restrict__ gs, const float* __restrict__ fmean,
                       const float* __restrict__ ch, const int* __restrict__ step,
                       const float* __restrict__ x,
                       float* __restrict__ synced, float* __restrict__ ncn,
                       float* __restrict__ comb) {
    int c = blockIdx.x, d = threadIdx.x;
    int f = c >> 7;
    float gm = 0.f;
    #pragma unroll
    for (int k = 0; k < 8; ++k) gm += fmean[k * 256 + d];
    gm *= 0.125f;
    float fm = fmean[f * 256 + d];
    float v = 0.85f * gs[c * 256 + d] + 0.15f * fm;
    if (((c & 127) < 32) && (*step > 5)) v = 0.85f * v + 0.15f * gm;
    synced[c * 256 + d] = v;
    ncn[c * 256 + d] = 0.7f * v + 0.3f * ch[c * 256 + d];
    if (c < N_LOOP) {
        comb[c * 512 + d] = x[d];
        comb[c * 512 + 256 + d] = v;
    }
}

// ---------------- evaluator layer 1: wave-per-row, 256 rows x 512, batch 32 ----------------
// rows 0..127 -> ea, 128..255 -> eg. h1ag[i][j] (j<128: ha, j>=128: hg)
__global__ void k_ev1(const float* __restrict__ comb,
                      const float* __restrict__ eaW1, const float* __restrict__ eab1,
                      const float* __restrict__ egW1, const float* __restrict__ egb1,
                      float* __restrict__ h1ag) {
    __shared__ __align__(16) float cl[N_LOOP * 512];   // 64 KB
    int t = threadIdx.x, l = t & 63, w = t >> 6;
    const float4* cg = (const float4*)comb;
    float4* c4 = (float4*)cl;
    for (int i = t; i < N_LOOP * 128; i += 256) c4[i] = cg[i];
    __syncthreads();
    int j = blockIdx.x * 4 + w;                        // 0..255
    const float* W = (j < 128) ? (eaW1 + j * 512) : (egW1 + (j - 128) * 512);
    float bias = (j < 128) ? eab1[j] : egb1[j - 128];
    const float4* w4 = (const float4*)W;
    float4 wa = w4[l], wb = w4[64 + l];
    for (int i = 0; i < N_LOOP; ++i) {
        const float4* ci = (const float4*)(cl + i * 512);
        float4 va = ci[l], vb = ci[64 + l];
        float acc = wa.x*va.x + wa.y*va.y + wa.z*va.z + wa.w*va.w
                  + wb.x*vb.x + wb.y*vb.y + wb.z*vb.z + wb.w*vb.w;
        acc = wave_reduce64(acc);
        if (l == 0) h1ag[i * 256 + j] = fmaxf(acc + bias, 0.f);
    }
}

// ---------------- evaluator layer 2: outputs = a - g. half-wave per row (256 rows x 128) ----------------
__global__ void k_ev2(const float* __restrict__ h1ag,
                      const float* __restrict__ eaW2, const float* __restrict__ eab2,
                      const float* __restrict__ egW2, const float* __restrict__ egb2,
                      float* __restrict__ outputs) {
    __shared__ __align__(16) float hl[N_LOOP * 256];   // 32 KB
    int t = threadIdx.x, l = t & 63, w = t >> 6;
    const float4* hg4 = (const float4*)h1ag;
    float4* h4 = (float4*)hl;
    for (int i = t; i < N_LOOP * 64; i += 256) h4[i] = hg4[i];
    __syncthreads();
    int half = l >> 5, sl = l & 31;
    int tr = (blockIdx.x * 4 + w) * 2 + half;          // output neuron 0..255
    float4 wa = ((const float4*)(eaW2 + tr * 128))[sl];
    float4 wg = ((const float4*)(egW2 + tr * 128))[sl];
    float bias = eab2[tr] - egb2[tr];
    for (int i = 0; i < N_LOOP; ++i) {
        float4 va = *(const float4*)(hl + i * 256 + sl * 4);
        float4 vg = *(const float4*)(hl + i * 256 + 128 + sl * 4);
        float acc = wa.x*va.x + wa.y*va.y + wa.z*va.z + wa.w*va.w
                  - (wg.x*vg.x + wg.y*vg.y + wg.z*vg.z + wg.w*vg.w);
        acc = wave_reduce32(acc);
        if (sl == 0) outputs[i * 256 + tr] = acc + bias;
    }
}

// ---------------- tensions[i] = mean(outputs[i]^2) ----------------
__global__ void k_tension(const float* __restrict__ outputs, float* __restrict__ tensions) {
    __shared__ float red[256];
    int i = blockIdx.x, t = threadIdx.x;
    float o = outputs[i * 256 + t];
    red[t] = o * o;
    __syncthreads();
    for (int m = 128; m; m >>= 1) { if (t < m) red[t] += red[t + m]; __syncthreads(); }
    if (t == 0) tensions[i] = red[0] * (1.f / 256.f);
}

// ---------------- GRU matvecs: wave-per-row over 768 rows, batch 32 ----------------
// u<512: store (gih+ghh) into rz[i][u]; u>=512: store i_n -> inb, h_n -> hnb
__global__ void k_gru(const float* __restrict__ outputs, const float* __restrict__ tensions,
                      const float* __restrict__ synced,
                      const float* __restrict__ Wih, const float* __restrict__ bih,
                      const float* __restrict__ Whh, const float* __restrict__ bhh,
                      float* __restrict__ rz, float* __restrict__ inb, float* __restrict__ hnb) {
    __shared__ __align__(16) float outs[N_LOOP * 256]; // 32 KB
    __shared__ __align__(16) float Hl[N_LOOP * 256];   // 32 KB
    __shared__ float tl[N_LOOP];
    int t = threadIdx.x, l = t & 63, w = t >> 6;
    {
        const float4* o4 = (const float4*)outputs;
        const float4* s4 = (const float4*)synced;
        float4* od = (float4*)outs;
        float4* hd = (float4*)Hl;
        for (int i = t; i < N_LOOP * 64; i += 256) { od[i] = o4[i]; hd[i] = s4[i]; }
        if (t < N_LOOP) tl[t] = tensions[t];
    }
    __syncthreads();
    int u = blockIdx.x * 4 + w;                        // 0..767
    const float* wr = Wih + (size_t)u * 257;
    float w0 = wr[4*l], w1 = wr[4*l+1], w2 = wr[4*l+2], w3 = wr[4*l+3];
    float wlast = wr[256];
    float4 wh = ((const float4*)(Whh + (size_t)u * 256))[l];
    float bg = bih[u], bh = bhh[u];
    bool isN = (u >= 512);
    for (int i = 0; i < N_LOOP; ++i) {
        const float* oi = outs + i * 256 + 4 * l;
        const float* hi = Hl + i * 256 + 4 * l;
        float ga = w0*oi[0] + w1*oi[1] + w2*oi[2] + w3*oi[3];
        float hh = wh.x*hi[0] + wh.y*hi[1] + wh.z*hi[2] + wh.w*hi[3];
        if (!isN) {
            float s = wave_reduce64(ga + hh);
            if (l == 0) rz[i * 512 + u] = s + bg + bh + wlast * tl[i];
        } else {
            float sg = wave_reduce64(ga);
            float sh = wave_reduce64(hh);
            if (l == 0) {
                inb[i * 256 + (u - 512)] = sg + bg + wlast * tl[i];
                hnb[i * 256 + (u - 512)] = sh + bh;
            }
        }
    }
}

// ---------------- GRU combine -> new_hiddens ----------------
__global__ void k_gru_fin(const float* __restrict__ rz, const float* __restrict__ inb,
                          const float* __restrict__ hnb, const float* __restrict__ synced,
                          float* __restrict__ out) {
    int i = blockIdx.x, d = threadIdx.x;
    float r = 1.f / (1.f + expf(-rz[i * 512 + d]));
    float z = 1.f / (1.f + expf(-rz[i * 512 + 256 + d]));
    float nc = tanhf(inb[i * 256 + d] + r * hnb[i * 256 + d]);
    float H = synced[i * 256 + d];
    out[259 + i * 256 + d] = (1.f - z) * nc + z * H;
}

// ---------------- fused disc layer-1 for real+fake ----------------
__global__ void k_disc1(const float* __restrict__ W1, const float* __restrict__ b1,
                        const float* __restrict__ real, const float* __restrict__ fake,
                        float* __restrict__ d1r, float* __restrict__ d1f) {
    __shared__ float sR[1024];
    __shared__ float sF[1024];
    int row = blockIdx.x, t = threadIdx.x;
    const float4* w4 = (const float4*)(W1 + (size_t)row * FLAT);
    const float4* r4 = (const float4*)real;
    const float4* f4 = (const float4*)fake;
    float aR = 0.f, aF = 0.f;
    for (int i = t; i < FLAT / 4; i += 1024) {
        float4 w = w4[i], r = r4[i], f = f4[i];
        aR += w.x*r.x + w.y*r.y + w.z*r.z + w.w*r.w;
        aF += w.x*f.x + w.y*f.y + w.z*f.z + w.w*f.w;
    }
    sR[t] = aR; sF[t] = aF;
    __syncthreads();
    for (int m = 512; m; m >>= 1) {
        if (t < m) { sR[t] += sR[t + m]; sF[t] += sF[t + m]; }
        __syncthreads();
    }
    if (t == 0) { d1r[row] = sR[0] + b1[row]; d1f[row] = sF[0] + b1[row]; }
}

// ---------------- disc layers 2+3 (block 0 = real, block 1 = fake) ----------------
__global__ void k_disc_tail(const float* __restrict__ W2, const float* __restrict__ b2,
                            const float* __restrict__ W3, const float* __restrict__ b3,
                            const float* __restrict__ d1r, const float* __restrict__ d1f,
                            float* __restrict__ out) {
    __shared__ __align__(16) float lv[512];
    __shared__ float l2[256];
    __shared__ float red[256];
    int b = blockIdx.x, t = threadIdx.x;
    const float* d1 = b ? d1f : d1r;
    for (int j = t; j < 512; j += 256) { float v = d1[j]; lv[j] = v > 0.f ? v : 0.2f * v; }
    __syncthreads();
    {
        float acc = b2[t];
        const float4* wr = (const float4*)(W2 + t * 512);
        const float4* l4 = (const float4*)lv;
        for (int k = 0; k < 128; ++k) {
            float4 w = wr[k], v = l4[k];
            acc += w.x*v.x + w.y*v.y + w.z*v.z + w.w*v.w;
        }
        l2[t] = acc > 0.f ? acc : 0.2f * acc;
    }
    __syncthreads();
    red[t] = l2[t] * W3[t];
    __syncthreads();
    for (int m = 128; m; m >>= 1) { if (t < m) red[t] += red[t + m]; __syncthreads(); }
    if (t == 0) { float v = red[0] + b3[0]; out[257 + b] = 1.f / (1.f + expf(-v)); }
}

// ---------------- mean_tension + softmax-weighted combine ----------------
__global__ void k_combine(const float* __restrict__ outputs, const float* __restrict__ tensions,
                          float* __restrict__ out) {
    __shared__ float w[32];
    __shared__ float ts[32];
    int t = threadIdx.x;
    if (t < 32) ts[t] = tensions[t];
    __syncthreads();
    if (t == 0) {
        float mx = ts[0];
        for (int i = 1; i < 32; ++i) mx = fmaxf(mx, ts[i]);
        float s = 0.f, mean = 0.f;
        for (int i = 0; i < 32; ++i) { float e = expf(ts[i] - mx); w[i] = e; s += e; mean += ts[i]; }
        float inv = 1.f / s;
        for (int i = 0; i < 32; ++i) w[i] *= inv;
        out[256] = mean * (1.f / 32.f);
    }
    __syncthreads();
    float c = 0.f;
    for (int i = 0; i < 32; ++i) c += w[i] * outputs[i * 256 + t];
    out[t] = c;
}

extern "C" void kernel_launch(void* const* d_in, const int* in_sizes, int n_in,
                              void* d_out, int out_size, void* d_ws, size_t ws_size,
                              hipStream_t stream) {
    const float* x     = (const float*)d_in[0];
    const float* noise = (const float*)d_in[1];
    const float* ch    = (const float*)d_in[2];
    const float* gW1   = (const float*)d_in[3];
    const float* gb1   = (const float*)d_in[4];
    const float* gW2   = (const float*)d_in[5];
    const float* gb2   = (const float*)d_in[6];
    const float* gW3   = (const float*)d_in[7];
    const float* gb3   = (const float*)d_in[8];
    const float* dW1   = (const float*)d_in[9];
    const float* db1   = (const float*)d_in[10];
    const float* dW2   = (const float*)d_in[11];
    const float* db2   = (const float*)d_in[12];
    const float* dW3   = (const float*)d_in[13];
    const float* db3   = (const float*)d_in[14];
    const float* eaW1  = (const float*)d_in[15];
    const float* eab1  = (const float*)d_in[16];
    const float* eaW2  = (const float*)d_in[17];
    const float* eab2  = (const float*)d_in[18];
    const float* egW1  = (const float*)d_in[19];
    const float* egb1  = (const float*)d_in[20];
    const float* egW2  = (const float*)d_in[21];
    const float* egb2  = (const float*)d_in[22];
    const float* Wih   = (const float*)d_in[23];
    const float* bih   = (const float*)d_in[24];
    const float* Whh   = (const float*)d_in[25];
    const float* bhh   = (const float*)d_in[26];
    const int*   step  = (const int*)d_in[27];

    float* out = (float*)d_out;
    float* ws  = (float*)d_ws;
    float* h1buf    = ws;                 // 256
    float* h2       = h1buf + 256;        // 512
    float* gs       = h2 + 512;           // 262144
    float* fmean    = gs + 262144;        // 2048
    float* synced   = fmean + 2048;       // 262144
    float* ncn      = synced + 262144;    // 262144
    float* comb     = ncn + 262144;       // 16384
    float* h1ag     = comb + 16384;       // 8192
    float* outputs  = h1ag + 8192;        // 8192
    float* tensions = outputs + 8192;     // 32
    float* rz       = tensions + 32;      // 16384
    float* inb      = rz + 16384;         // 8192
    float* hnb      = inb + 8192;         // 8192
    float* d1r      = hnb + 8192;         // 512
    float* d1f      = d1r + 512;          // 512

    k_gen_h1<<<64, 256, 0, stream>>>(x, noise, gW1, gb1, h1buf);
    k_gen_h2<<<128, 256, 0, stream>>>(h1buf, gW2, gb2, h2);
    k_gen_big<<<FLAT / 4, 256, 0, stream>>>(gW3, gb3, h2, gs);
    k_fmean<<<32, 256, 0, stream>>>(gs, fmean);
    k_sync<<<1024, 256, 0, stream>>>(gs, fmean, ch, step, x, synced, ncn, comb);
    k_ev1<<<64, 256, 0, stream>>>(comb, eaW1, eab1, egW1, egb1, h1ag);
    k_ev2<<<32, 256, 0, stream>>>(h1ag, eaW2, eab2, egW2, egb2, outputs);
    k_tension<<<32, 256, 0, stream>>>(outputs, tensions);
    k_gru<<<192, 256, 0, stream>>>(outputs, tensions, synced, Wih, bih, Whh, bhh, rz, inb, hnb);
    k_gru_fin<<<32, 256, 0, stream>>>(rz, inb, hnb, synced, out);
    k_disc1<<<512, 1024, 0, stream>>>(dW1, db1, ncn, gs, d1r, d1f);
    k_disc_tail<<<2, 256, 0, stream>>>(dW2, db2, dW3, db3, d1r, d1f, out);
    k_combine<<<1, 256, 0, stream>>>(outputs, tensions, out);
}